// Round 21
// baseline (569.221 us; speedup 1.0000x reference)
//
#include <hip/hip_runtime.h>
#include <hip/hip_bf16.h>

#define N_EMBD 768
#define N_HEADS 12
#define HEAD_DIM 64

typedef __attribute__((ext_vector_type(4))) float f32x4;
typedef __attribute__((ext_vector_type(8))) short s16x8;

__device__ __forceinline__ float bf2f(unsigned short u) {
  union { unsigned int i; float f; } z;
  z.i = ((unsigned int)u) << 16;
  return z.f;
}

__device__ __forceinline__ void gload_lds16(const void* g, void* l) {
  __builtin_amdgcn_global_load_lds(
      (const __attribute__((address_space(1))) void*)g,
      (__attribute__((address_space(3))) void*)l, 16, 0, 0);
}

__device__ __forceinline__ float gelu_f(float x) {
  const float c = 0.7978845608028654f;
  float u = c * (x + 0.044715f * x * x * x);
  float t = 1.0f - 2.0f / (__expf(2.0f * u) + 1.0f);
  return 0.5f * x * (1.0f + t);
}

// ---------------- weight fp32 -> bf16 (all four in one launch) ----------------
__global__ void cvt4_kernel(const float* __restrict__ s0, __hip_bfloat16* d0,
                            const float* __restrict__ s1, __hip_bfloat16* d1,
                            const float* __restrict__ s2, __hip_bfloat16* d2,
                            const float* __restrict__ s3, __hip_bfloat16* d3,
                            int n0, int n1, int n2, int n3) {
  int i = blockIdx.x * 256 + threadIdx.x;
  if (i < n0) { d0[i] = __float2bfloat16(s0[i]); return; }
  i -= n0;
  if (i < n1) { d1[i] = __float2bfloat16(s1[i]); return; }
  i -= n1;
  if (i < n2) { d2[i] = __float2bfloat16(s2[i]); return; }
  i -= n2;
  if (i < n3) d3[i] = __float2bfloat16(s3[i]);
}

// ---------------- fused LayerNorm: fp32 in -> bf16 out ----------------
__global__ __launch_bounds__(256) void ln_kernel(
    const float* __restrict__ x, const float* __restrict__ g,
    const float* __restrict__ b, __hip_bfloat16* __restrict__ out) {
  __shared__ float red[8];
  const int row = blockIdx.x;
  const int tid = threadIdx.x;
  const float* xr = x + (size_t)row * N_EMBD;
  float v0 = xr[tid], v1 = xr[tid + 256], v2 = xr[tid + 512];
  float s = v0 + v1 + v2;
#pragma unroll
  for (int m = 32; m >= 1; m >>= 1) s += __shfl_xor(s, m);
  if ((tid & 63) == 0) red[tid >> 6] = s;
  __syncthreads();
  float mu = (red[0] + red[1] + red[2] + red[3]) * (1.0f / 768.0f);
  float d0 = v0 - mu, d1 = v1 - mu, d2 = v2 - mu;
  float ss = d0 * d0 + d1 * d1 + d2 * d2;
  __syncthreads();
#pragma unroll
  for (int m = 32; m >= 1; m >>= 1) ss += __shfl_xor(ss, m);
  if ((tid & 63) == 0) red[4 + (tid >> 6)] = ss;
  __syncthreads();
  float var = (red[4] + red[5] + red[6] + red[7]) * (1.0f / 768.0f);
  float rstd = rsqrtf(var + 1e-5f);
  __hip_bfloat16* orow = out + (size_t)row * N_EMBD;
  orow[tid]       = __float2bfloat16(d0 * rstd * g[tid]       + b[tid]);
  orow[tid + 256] = __float2bfloat16(d1 * rstd * g[tid + 256] + b[tid + 256]);
  orow[tid + 512] = __float2bfloat16(d2 * rstd * g[tid + 512] + b[tid + 512]);
}

// ---------------- barrier-free direct-to-register GEMM (all four) ----------------
// No LDS, no s_barrier: each wave loads its own MFMA fragments global->VGPR
// (lane (fr,fq) reads contiguous 16B at row*K + fq*8; a wave covers 16 rows
// x 64B -- L1/L2 friendly). 1-tile-deep register double buffer; compiler
// inserts counted vmcnt. Waves never convoy; duplication (2 waves share
// each operand half) is absorbed by L1/L2 (HBM at 11%).
#define TILE_M 128
#define TILE_N 128

template <int EPI>
__global__ __launch_bounds__(256) void gemm_reg(
    const __hip_bfloat16* __restrict__ A, const __hip_bfloat16* __restrict__ W,
    const float* __restrict__ bias, const float* __restrict__ resid,
    __hip_bfloat16* __restrict__ outb, float* __restrict__ outf,
    int M, int N, int K) {
  const int tid = threadIdx.x;
  const int lane = tid & 63;
  const int wave = tid >> 6;

  // 2D XCD region swizzle (R18-verified: per-XCD operand footprint L2-fits)
  const int nbx = gridDim.x, nby = gridDim.y;
  int brow, bcol;
  if ((nby & 3) == 0 && (nbx & 1) == 0) {
    const int b0 = blockIdx.y * nbx + blockIdx.x;
    const int xcd = b0 & 7;
    const int idx = b0 >> 3;
    const int RW = nbx >> 1;
    brow = (xcd >> 1) * (nby >> 2) + idx / RW;
    bcol = (xcd & 1) * RW + idx % RW;
  } else {
    brow = blockIdx.y; bcol = blockIdx.x;
  }
  const int m0 = brow * TILE_M;
  const int n0 = bcol * TILE_N;
  const int wr = wave >> 1, wc = wave & 1;
  const int fr = lane & 15;
  const int fq = lane >> 4;

  f32x4 acc[4][4];
#pragma unroll
  for (int i = 0; i < 4; ++i)
#pragma unroll
    for (int j = 0; j < 4; ++j) acc[i][j] = f32x4{0.f, 0.f, 0.f, 0.f};

  const __hip_bfloat16* Ab[4];
  const __hip_bfloat16* Wb[4];
#pragma unroll
  for (int i = 0; i < 4; ++i) {
    Ab[i] = A + (size_t)(m0 + wr * 64 + i * 16 + fr) * K + fq * 8;
    Wb[i] = W + (size_t)(n0 + wc * 64 + i * 16 + fr) * K + fq * 8;
  }

  const int nk = K / 32;  // 24 or 96: always even
  s16x8 a0[4], b0[4], a1[4], b1[4];

  auto ld = [&](s16x8 (&af)[4], s16x8 (&bf_)[4], int k0) {
#pragma unroll
    for (int i = 0; i < 4; ++i) af[i] = *(const s16x8*)(Ab[i] + k0);
#pragma unroll
    for (int i = 0; i < 4; ++i) bf_[i] = *(const s16x8*)(Wb[i] + k0);
  };
  auto mm = [&](s16x8 (&af)[4], s16x8 (&bf_)[4]) {
#pragma unroll
    for (int mi = 0; mi < 4; ++mi)
#pragma unroll
      for (int ni = 0; ni < 4; ++ni)
        acc[mi][ni] = __builtin_amdgcn_mfma_f32_16x16x32_bf16(
            af[mi], bf_[ni], acc[mi][ni], 0, 0, 0);
  };

  ld(a0, b0, 0);
  for (int t = 0; t < nk; t += 2) {
    if (t + 1 < nk) ld(a1, b1, (t + 1) * 32);  // in flight under mm(a0)
    mm(a0, b0);
    if (t + 2 < nk) ld(a0, b0, (t + 2) * 32);  // in flight under mm(a1)
    if (t + 1 < nk) mm(a1, b1);
  }

  const int crow = fq * 4;
  const int ccol = fr;
#pragma unroll
  for (int mi = 0; mi < 4; ++mi) {
#pragma unroll
    for (int ni = 0; ni < 4; ++ni) {
      const int col = n0 + wc * 64 + ni * 16 + ccol;
      const float bv = bias[col];
#pragma unroll
      for (int j = 0; j < 4; ++j) {
        const int row = m0 + wr * 64 + mi * 16 + crow + j;
        float v = acc[mi][ni][j] + bv;
        const size_t o = (size_t)row * N + col;
        if (EPI == 0) {
          outb[o] = __float2bfloat16(v);
        } else if (EPI == 1) {
          outb[o] = __float2bfloat16(gelu_f(v));
        } else {
          outf[o] = resid[o] + v;
        }
      }
    }
  }
}

// ---------------- MFMA causal flash attention, v5 (R19 anchor, 292.05us) ----------------
#define AP 72

__global__ __launch_bounds__(256) void attn_mfma(
    const __hip_bfloat16* __restrict__ qkv, __hip_bfloat16* __restrict__ y,
    int T) {
  __shared__ __hip_bfloat16 ks[2][64 * AP];
  __shared__ __hip_bfloat16 vt[2][64 * AP];
  __shared__ __hip_bfloat16 ps[4][16 * AP];
  const int tid = threadIdx.x;
  const int lane = tid & 63;
  const int wave = tid >> 6;

  // chunked XCD swizzle: each XCD owns 96 consecutive virt ids (6 bh's)
  const int nbx = gridDim.x;  // 16
  const int nwg = nbx * gridDim.y;
  int bid = blockIdx.y * nbx + blockIdx.x;
  if ((nwg & 7) == 0) bid = (bid & 7) * (nwg >> 3) + (bid >> 3);
  const int bx = bid % nbx;
  const int bh = bid / nbx;
  const int b = bh / N_HEADS, h = bh % N_HEADS;

  const int nq = T / 64;
  const int qa0 = bx * 64;
  const int qb0 = (nq - 1 - bx) * 64;
  const size_t ldq = 3 * N_EMBD;
  const __hip_bfloat16* qb_ = qkv + (size_t)b * T * ldq + h * HEAD_DIM;
  const __hip_bfloat16* kb = qb_ + N_EMBD;
  const __hip_bfloat16* vb = qb_ + 2 * N_EMBD;

  const int fr = lane & 15;
  const int fo = (lane >> 4) * 8;
  const int crow = (lane >> 4) * 4;

  const float qs = 0.125f * 1.44269504f;
  auto loadq = [&](int qrow, int o) -> s16x8 {
    s16x8 v = *(const s16x8*)(qb_ + (size_t)qrow * ldq + o);
    s16x8 r;
#pragma unroll
    for (int i = 0; i < 8; ++i) {
      float f = bf2f((unsigned short)v[i]) * qs;
      __hip_bfloat16 hb = __float2bfloat16(f);
      r[i] = *reinterpret_cast<short*>(&hb);
    }
    return r;
  };
  s16x8 qfa0 = loadq(qa0 + wave * 16 + fr, fo);
  s16x8 qfa1 = loadq(qa0 + wave * 16 + fr, fo + 32);
  s16x8 qfb0 = loadq(qb0 + wave * 16 + fr, fo);
  s16x8 qfb1 = loadq(qb0 + wave * 16 + fr, fo + 32);

  f32x4 oa[4], ob[4];
#pragma unroll
  for (int j = 0; j < 4; ++j) {
    oa[j] = f32x4{0.f, 0.f, 0.f, 0.f};
    ob[j] = f32x4{0.f, 0.f, 0.f, 0.f};
  }
  float m_a = -1e30f, l_a = 0.f, m_b = -1e30f, l_b = 0.f;

  s16x8 kr0, kr1, vr0, vr1;
  const int krow0 = tid >> 3;
  const int kcol = (tid & 7) * 8;
  const int vkey = 2 * (lane & 31);
  const int vd0 = wave * 16 + (lane >> 5) * 8;

  auto loadKV = [&](int kt) {
    kr0 = *(const s16x8*)(kb + (size_t)(kt + krow0) * ldq + kcol);
    kr1 = *(const s16x8*)(kb + (size_t)(kt + 32 + krow0) * ldq + kcol);
    vr0 = *(const s16x8*)(vb + (size_t)(kt + vkey) * ldq + vd0);
    vr1 = *(const s16x8*)(vb + (size_t)(kt + vkey + 1) * ldq + vd0);
  };
  auto writeKV = [&](int bufi) {
    *(s16x8*)&ks[bufi][krow0 * AP + kcol] = kr0;
    *(s16x8*)&ks[bufi][(32 + krow0) * AP + kcol] = kr1;
#pragma unroll
    for (int i = 0; i < 8; ++i) {
      unsigned u = (unsigned short)vr0[i] | ((unsigned)(unsigned short)vr1[i] << 16);
      *(unsigned*)&vt[bufi][(vd0 + i) * AP + vkey] = u;
    }
  };

  auto process = [&](int bufi, const s16x8& q0f, const s16x8& q1f,
                     f32x4 (&o)[4], float& m_, float& l_, int tq0, bool diag,
                     int kt) {
    f32x4 sv[4];
#pragma unroll
    for (int sub = 0; sub < 4; ++sub) {
      s16x8 k0 = *(const s16x8*)&ks[bufi][(sub * 16 + fr) * AP + fo];
      s16x8 k1 = *(const s16x8*)&ks[bufi][(sub * 16 + fr) * AP + 32 + fo];
      f32x4 acc = f32x4{0.f, 0.f, 0.f, 0.f};
      acc = __builtin_amdgcn_mfma_f32_16x16x32_bf16(k0, q0f, acc, 0, 0, 0);
      acc = __builtin_amdgcn_mfma_f32_16x16x32_bf16(k1, q1f, acc, 0, 0, 0);
      sv[sub] = acc;
    }
    const int qg = tq0 + wave * 16 + fr;
    if (diag) {
#pragma unroll
      for (int sub = 0; sub < 4; ++sub)
#pragma unroll
        for (int j = 0; j < 4; ++j)
          if (kt + sub * 16 + crow + j > qg) sv[sub][j] = -1e30f;
    }
    float g0 = fmaxf(fmaxf(sv[0][0], sv[0][1]), fmaxf(sv[0][2], sv[0][3]));
    float g1 = fmaxf(fmaxf(sv[1][0], sv[1][1]), fmaxf(sv[1][2], sv[1][3]));
    float g2 = fmaxf(fmaxf(sv[2][0], sv[2][1]), fmaxf(sv[2][2], sv[2][3]));
    float g3 = fmaxf(fmaxf(sv[3][0], sv[3][1]), fmaxf(sv[3][2], sv[3][3]));
    float t = fmaxf(fmaxf(g0, g1), fmaxf(g2, g3));
    t = fmaxf(t, __shfl_xor(t, 16));
    t = fmaxf(t, __shfl_xor(t, 32));
    const bool resc = t > m_ + 8.0f;  // T13 defer-max
    const float corr = resc ? exp2f(m_ - t) : 1.0f;
    if (resc) m_ = t;
    float rs = 0.f;
#pragma unroll
    for (int sub = 0; sub < 4; ++sub) {
      float p0 = exp2f(sv[sub][0] - m_);
      float p1 = exp2f(sv[sub][1] - m_);
      float p2 = exp2f(sv[sub][2] - m_);
      float p3 = exp2f(sv[sub][3] - m_);
      rs += (p0 + p1) + (p2 + p3);
      __hip_bfloat162 pk01 = __float22bfloat162_rn(float2{p0, p1});
      __hip_bfloat162 pk23 = __float22bfloat162_rn(float2{p2, p3});
      uint2 u;
      u.x = *reinterpret_cast<unsigned*>(&pk01);
      u.y = *reinterpret_cast<unsigned*>(&pk23);
      *(uint2*)&ps[wave][fr * AP + sub * 16 + crow] = u;  // ds_write_b64
    }
    rs += __shfl_xor(rs, 16);
    rs += __shfl_xor(rs, 32);
    l_ = l_ * corr + rs;
    if (__any(resc)) {
#pragma unroll
      for (int j = 0; j < 4; ++j) {
        const float cj = __shfl(corr, (lane & 0x30) | (crow + j));
#pragma unroll
        for (int ds = 0; ds < 4; ++ds) o[ds][j] *= cj;
      }
    }
    s16x8 pf0 = *(const s16x8*)&ps[wave][fr * AP + fo];
    s16x8 pf1 = *(const s16x8*)&ps[wave][fr * AP + 32 + fo];
#pragma unroll
    for (int ds = 0; ds < 4; ++ds) {
      s16x8 v0 = *(const s16x8*)&vt[bufi][(ds * 16 + fr) * AP + fo];
      s16x8 v1 = *(const s16x8*)&vt[bufi][(ds * 16 + fr) * AP + 32 + fo];
      o[ds] = __builtin_amdgcn_mfma_f32_16x16x32_bf16(pf0, v0, o[ds], 0, 0, 0);
      o[ds] = __builtin_amdgcn_mfma_f32_16x16x32_bf16(pf1, v1, o[ds], 0, 0, 0);
    }
  };

  loadKV(0);
  writeKV(0);
  __syncthreads();
  int cur = 0;
  for (int kt = 0; kt <= qb0; kt += 64) {
    const bool hasnext = (kt + 64 <= qb0);
    if (hasnext) loadKV(kt + 64);
    if (kt <= qa0)
      process(cur, qfa0, qfa1, oa, m_a, l_a, qa0, kt == qa0, kt);
    process(cur, qfb0, qfb1, ob, m_b, l_b, qb0, kt == qb0, kt);
    if (hasnext) writeKV(cur ^ 1);
    __syncthreads();
    cur ^= 1;
  }

#pragma unroll
  for (int j = 0; j < 4; ++j) {
    const float la_j = __shfl(l_a, (lane & 0x30) | (crow + j));
    const float lb_j = __shfl(l_b, (lane & 0x30) | (crow + j));
    const float inva = 1.0f / la_j;
    const float invb = 1.0f / lb_j;
    __hip_bfloat16* ya =
        y + (size_t)(b * T + qa0 + wave * 16 + crow + j) * N_EMBD + h * HEAD_DIM;
    __hip_bfloat16* yb =
        y + (size_t)(b * T + qb0 + wave * 16 + crow + j) * N_EMBD + h * HEAD_DIM;
#pragma unroll
    for (int ds = 0; ds < 4; ++ds) {
      ya[ds * 16 + fr] = __float2bfloat16(oa[ds][j] * inva);
      yb[ds * 16 + fr] = __float2bfloat16(ob[ds][j] * invb);
    }
  }
}

// ---------------- launch ----------------
extern "C" void kernel_launch(void* const* d_in, const int* in_sizes, int n_in,
                              void* d_out, int out_size, void* d_ws,
                              size_t ws_size, hipStream_t stream) {
  const int B = 4, T = 2048, C = N_EMBD;
  const int M = B * T;  // 8192

  const float* x      = (const float*)d_in[0];
  const float* ln1_g  = (const float*)d_in[1];
  const float* ln1_b  = (const float*)d_in[2];
  const float* attn_w = (const float*)d_in[3];
  const float* attn_b = (const float*)d_in[4];
  const float* proj_w = (const float*)d_in[5];
  const float* proj_b = (const float*)d_in[6];
  const float* ln2_g  = (const float*)d_in[7];
  const float* ln2_b  = (const float*)d_in[8];
  const float* fc_w   = (const float*)d_in[9];
  const float* fc_b   = (const float*)d_in[10];
  const float* fc2_w  = (const float*)d_in[11];
  const float* fc2_b  = (const float*)d_in[12];
  float* out = (float*)d_out;

  char* p = (char*)d_ws;
  size_t off = 0;
  auto take = [&](size_t bytes) -> void* {
    void* q = p + off;
    off += (bytes + 1023) & ~(size_t)1023;
    return q;
  };

  __hip_bfloat16* wqkv  = (__hip_bfloat16*)take((size_t)3 * C * C * 2);
  __hip_bfloat16* wproj = (__hip_bfloat16*)take((size_t)C * C * 2);
  __hip_bfloat16* wfc   = (__hip_bfloat16*)take((size_t)4 * C * C * 2);
  __hip_bfloat16* wfc2  = (__hip_bfloat16*)take((size_t)4 * C * C * 2);
  __hip_bfloat16* hbuf  = (__hip_bfloat16*)take((size_t)M * C * 2);
  __hip_bfloat16* big   = (__hip_bfloat16*)take((size_t)M * 4 * C * 2);
  __hip_bfloat16* ybuf  = (__hip_bfloat16*)take((size_t)M * C * 2);
  float*          x1    = (float*)take((size_t)M * C * 4);

  {
    const int n0 = 3 * C * C, n1 = C * C, n2 = 4 * C * C, n3 = 4 * C * C;
    const int ntot = n0 + n1 + n2 + n3;
    cvt4_kernel<<<(ntot + 255) / 256, 256, 0, stream>>>(
        attn_w, wqkv, proj_w, wproj, fc_w, wfc, fc2_w, wfc2, n0, n1, n2, n3);
  }

  ln_kernel<<<M, 256, 0, stream>>>(x, ln1_g, ln1_b, hbuf);
  gemm_reg<0><<<dim3(3 * C / TILE_N, M / TILE_M), 256, 0, stream>>>(
      hbuf, wqkv, attn_b, nullptr, big, nullptr, M, 3 * C, C);
  attn_mfma<<<dim3(T / 128, B * N_HEADS), 256, 0, stream>>>(big, ybuf, T);
  gemm_reg<2><<<dim3(C / TILE_N, M / TILE_M), 256, 0, stream>>>(
      ybuf, wproj, proj_b, x, nullptr, x1, M, C, C);
  ln_kernel<<<M, 256, 0, stream>>>(x1, ln2_g, ln2_b, hbuf);
  gemm_reg<1><<<dim3(4 * C / TILE_N, M / TILE_M), 256, 0, stream>>>(
      hbuf, wfc, fc_b, nullptr, big, nullptr, M, 4 * C, C);
  gemm_reg<2><<<dim3(C / TILE_N, M / TILE_M), 256, 0, stream>>>(
      big, wfc2, fc2_b, x1, nullptr, out, M, C, 4 * C);
}

// Round 22
// 292.229 us; speedup vs baseline: 1.9479x; 1.9479x over previous
//
#include <hip/hip_runtime.h>
#include <hip/hip_bf16.h>

#define N_EMBD 768
#define N_HEADS 12
#define HEAD_DIM 64

typedef __attribute__((ext_vector_type(4))) float f32x4;
typedef __attribute__((ext_vector_type(8))) short s16x8;

__device__ __forceinline__ float bf2f(unsigned short u) {
  union { unsigned int i; float f; } z;
  z.i = ((unsigned int)u) << 16;
  return z.f;
}

__device__ __forceinline__ void gload_lds16(const void* g, void* l) {
  __builtin_amdgcn_global_load_lds(
      (const __attribute__((address_space(1))) void*)g,
      (__attribute__((address_space(3))) void*)l, 16, 0, 0);
}

__device__ __forceinline__ float gelu_f(float x) {
  const float c = 0.7978845608028654f;
  float u = c * (x + 0.044715f * x * x * x);
  float t = 1.0f - 2.0f / (__expf(2.0f * u) + 1.0f);
  return 0.5f * x * (1.0f + t);
}

// ---------------- weight fp32 -> bf16 (all four in one launch) ----------------
__global__ void cvt4_kernel(const float* __restrict__ s0, __hip_bfloat16* d0,
                            const float* __restrict__ s1, __hip_bfloat16* d1,
                            const float* __restrict__ s2, __hip_bfloat16* d2,
                            const float* __restrict__ s3, __hip_bfloat16* d3,
                            int n0, int n1, int n2, int n3) {
  int i = blockIdx.x * 256 + threadIdx.x;
  if (i < n0) { d0[i] = __float2bfloat16(s0[i]); return; }
  i -= n0;
  if (i < n1) { d1[i] = __float2bfloat16(s1[i]); return; }
  i -= n1;
  if (i < n2) { d2[i] = __float2bfloat16(s2[i]); return; }
  i -= n2;
  if (i < n3) d3[i] = __float2bfloat16(s3[i]);
}

// ---------------- fused LayerNorm: fp32 in -> bf16 out ----------------
__global__ __launch_bounds__(256) void ln_kernel(
    const float* __restrict__ x, const float* __restrict__ g,
    const float* __restrict__ b, __hip_bfloat16* __restrict__ out) {
  __shared__ float red[8];
  const int row = blockIdx.x;
  const int tid = threadIdx.x;
  const float* xr = x + (size_t)row * N_EMBD;
  float v0 = xr[tid], v1 = xr[tid + 256], v2 = xr[tid + 512];
  float s = v0 + v1 + v2;
#pragma unroll
  for (int m = 32; m >= 1; m >>= 1) s += __shfl_xor(s, m);
  if ((tid & 63) == 0) red[tid >> 6] = s;
  __syncthreads();
  float mu = (red[0] + red[1] + red[2] + red[3]) * (1.0f / 768.0f);
  float d0 = v0 - mu, d1 = v1 - mu, d2 = v2 - mu;
  float ss = d0 * d0 + d1 * d1 + d2 * d2;
  __syncthreads();
#pragma unroll
  for (int m = 32; m >= 1; m >>= 1) ss += __shfl_xor(ss, m);
  if ((tid & 63) == 0) red[4 + (tid >> 6)] = ss;
  __syncthreads();
  float var = (red[4] + red[5] + red[6] + red[7]) * (1.0f / 768.0f);
  float rstd = rsqrtf(var + 1e-5f);
  __hip_bfloat16* orow = out + (size_t)row * N_EMBD;
  orow[tid]       = __float2bfloat16(d0 * rstd * g[tid]       + b[tid]);
  orow[tid + 256] = __float2bfloat16(d1 * rstd * g[tid + 256] + b[tid + 256]);
  orow[tid + 512] = __float2bfloat16(d2 * rstd * g[tid + 512] + b[tid + 512]);
}

// ---------------- 128x128 GEMM, counted-vmcnt + XOR swizzle + 2D XCD regions ----------------
#define TILE_M 128
#define TILE_N 128
#define TILE_K 32

template <int EPI>
__global__ __launch_bounds__(256) void gemm_bt(
    const __hip_bfloat16* __restrict__ A, const __hip_bfloat16* __restrict__ W,
    const float* __restrict__ bias, const float* __restrict__ resid,
    __hip_bfloat16* __restrict__ outb, float* __restrict__ outf,
    int M, int N, int K) {
  __shared__ __hip_bfloat16 smA[2][TILE_M * TILE_K];
  __shared__ __hip_bfloat16 smB[2][TILE_N * TILE_K];
  const int tid = threadIdx.x;
  const int lane = tid & 63;
  const int wave = tid >> 6;

  const int nbx = gridDim.x;   // col tiles
  const int nby = gridDim.y;   // row tiles
  int brow, bcol;
  if ((nby & 3) == 0 && (nbx & 1) == 0) {
    const int b0 = blockIdx.y * nbx + blockIdx.x;
    const int xcd = b0 & 7;
    const int idx = b0 >> 3;
    const int RW = nbx >> 1;          // region width
    brow = (xcd >> 1) * (nby >> 2) + idx / RW;
    bcol = (xcd & 1) * RW + idx % RW;
  } else {
    brow = blockIdx.y; bcol = blockIdx.x;
  }
  const int m0 = brow * TILE_M;
  const int n0 = bcol * TILE_N;
  const int wr = wave >> 1, wc = wave & 1;

  f32x4 acc[4][4];
#pragma unroll
  for (int i = 0; i < 4; ++i)
#pragma unroll
    for (int j = 0; j < 4; ++j) acc[i][j] = f32x4{0.f, 0.f, 0.f, 0.f};

  const int ar0 = tid >> 2;
  const int ac0 = (((tid & 3) ^ ((ar0 >> 1) & 3))) * 8;
  const __hip_bfloat16* Abase0 = A + (size_t)(m0 + ar0) * K + ac0;
  const __hip_bfloat16* Abase1 = A + (size_t)(m0 + 64 + ar0) * K + ac0;
  const __hip_bfloat16* Wbase0 = W + (size_t)(n0 + ar0) * K + ac0;
  const __hip_bfloat16* Wbase1 = W + (size_t)(n0 + 64 + ar0) * K + ac0;

  auto stage = [&](int buf, int k0) {
    gload_lds16(Abase0 + k0, &smA[buf][wave * 512]);
    gload_lds16(Abase1 + k0, &smA[buf][2048 + wave * 512]);
    gload_lds16(Wbase0 + k0, &smB[buf][wave * 512]);
    gload_lds16(Wbase1 + k0, &smB[buf][2048 + wave * 512]);
  };

  const int rA = lane & 15;
  const int fq = lane >> 4;
  const int nk = K / TILE_K;

  stage(0, 0);

  int cur = 0;
  for (int t = 0; t < nk; ++t) {
    asm volatile("s_waitcnt vmcnt(0)" ::: "memory");
    asm volatile("s_barrier" ::: "memory");
    if (t + 1 < nk) stage(cur ^ 1, (t + 1) * TILE_K);

    s16x8 af[4], bfr[4];
#pragma unroll
    for (int mi = 0; mi < 4; ++mi) {
      const int row = wr * 64 + mi * 16 + rA;
      const int g = fq ^ ((row >> 1) & 3);
      af[mi] = *(const s16x8*)&smA[cur][row * TILE_K + g * 8];
    }
#pragma unroll
    for (int ni = 0; ni < 4; ++ni) {
      const int row = wc * 64 + ni * 16 + rA;
      const int g = fq ^ ((row >> 1) & 3);
      bfr[ni] = *(const s16x8*)&smB[cur][row * TILE_K + g * 8];
    }
#pragma unroll
    for (int mi = 0; mi < 4; ++mi)
#pragma unroll
      for (int ni = 0; ni < 4; ++ni)
        acc[mi][ni] = __builtin_amdgcn_mfma_f32_16x16x32_bf16(
            af[mi], bfr[ni], acc[mi][ni], 0, 0, 0);
    cur ^= 1;
  }

  const int crow = (lane >> 4) * 4;
  const int ccol = lane & 15;
#pragma unroll
  for (int mi = 0; mi < 4; ++mi) {
#pragma unroll
    for (int ni = 0; ni < 4; ++ni) {
      const int col = n0 + wc * 64 + ni * 16 + ccol;
      const float bv = bias[col];
#pragma unroll
      for (int j = 0; j < 4; ++j) {
        const int row = m0 + wr * 64 + mi * 16 + crow + j;
        float v = acc[mi][ni][j] + bv;
        const size_t o = (size_t)row * N + col;
        if (EPI == 0) {
          outb[o] = __float2bfloat16(v);
        } else if (EPI == 1) {
          outb[o] = __float2bfloat16(gelu_f(v));
        } else {
          outf[o] = resid[o] + v;
        }
      }
    }
  }
}

// ---------------- MFMA causal flash attention, v5 (R19-verified best) ----------------
#define AP 72

__global__ __launch_bounds__(256) void attn_mfma(
    const __hip_bfloat16* __restrict__ qkv, __hip_bfloat16* __restrict__ y,
    int T) {
  __shared__ __hip_bfloat16 ks[2][64 * AP];
  __shared__ __hip_bfloat16 vt[2][64 * AP];
  __shared__ __hip_bfloat16 ps[4][16 * AP];
  const int tid = threadIdx.x;
  const int lane = tid & 63;
  const int wave = tid >> 6;

  // chunked XCD swizzle: each XCD owns 96 consecutive virt ids (6 bh's)
  const int nbx = gridDim.x;  // 16
  const int nwg = nbx * gridDim.y;
  int bid = blockIdx.y * nbx + blockIdx.x;
  if ((nwg & 7) == 0) bid = (bid & 7) * (nwg >> 3) + (bid >> 3);
  const int bx = bid % nbx;
  const int bh = bid / nbx;
  const int b = bh / N_HEADS, h = bh % N_HEADS;

  const int nq = T / 64;
  const int qa0 = bx * 64;
  const int qb0 = (nq - 1 - bx) * 64;
  const size_t ldq = 3 * N_EMBD;
  const __hip_bfloat16* qb_ = qkv + (size_t)b * T * ldq + h * HEAD_DIM;
  const __hip_bfloat16* kb = qb_ + N_EMBD;
  const __hip_bfloat16* vb = qb_ + 2 * N_EMBD;

  const int fr = lane & 15;
  const int fo = (lane >> 4) * 8;
  const int crow = (lane >> 4) * 4;

  const float qs = 0.125f * 1.44269504f;
  auto loadq = [&](int qrow, int o) -> s16x8 {
    s16x8 v = *(const s16x8*)(qb_ + (size_t)qrow * ldq + o);
    s16x8 r;
#pragma unroll
    for (int i = 0; i < 8; ++i) {
      float f = bf2f((unsigned short)v[i]) * qs;
      __hip_bfloat16 hb = __float2bfloat16(f);
      r[i] = *reinterpret_cast<short*>(&hb);
    }
    return r;
  };
  s16x8 qfa0 = loadq(qa0 + wave * 16 + fr, fo);
  s16x8 qfa1 = loadq(qa0 + wave * 16 + fr, fo + 32);
  s16x8 qfb0 = loadq(qb0 + wave * 16 + fr, fo);
  s16x8 qfb1 = loadq(qb0 + wave * 16 + fr, fo + 32);

  f32x4 oa[4], ob[4];
#pragma unroll
  for (int j = 0; j < 4; ++j) {
    oa[j] = f32x4{0.f, 0.f, 0.f, 0.f};
    ob[j] = f32x4{0.f, 0.f, 0.f, 0.f};
  }
  float m_a = -1e30f, l_a = 0.f, m_b = -1e30f, l_b = 0.f;

  s16x8 kr0, kr1, vr0, vr1;
  const int krow0 = tid >> 3;
  const int kcol = (tid & 7) * 8;
  const int vkey = 2 * (lane & 31);
  const int vd0 = wave * 16 + (lane >> 5) * 8;

  auto loadKV = [&](int kt) {
    kr0 = *(const s16x8*)(kb + (size_t)(kt + krow0) * ldq + kcol);
    kr1 = *(const s16x8*)(kb + (size_t)(kt + 32 + krow0) * ldq + kcol);
    vr0 = *(const s16x8*)(vb + (size_t)(kt + vkey) * ldq + vd0);
    vr1 = *(const s16x8*)(vb + (size_t)(kt + vkey + 1) * ldq + vd0);
  };
  auto writeKV = [&](int bufi) {
    *(s16x8*)&ks[bufi][krow0 * AP + kcol] = kr0;
    *(s16x8*)&ks[bufi][(32 + krow0) * AP + kcol] = kr1;
#pragma unroll
    for (int i = 0; i < 8; ++i) {
      unsigned u = (unsigned short)vr0[i] | ((unsigned)(unsigned short)vr1[i] << 16);
      *(unsigned*)&vt[bufi][(vd0 + i) * AP + vkey] = u;
    }
  };

  auto process = [&](int bufi, const s16x8& q0f, const s16x8& q1f,
                     f32x4 (&o)[4], float& m_, float& l_, int tq0, bool diag,
                     int kt) {
    f32x4 sv[4];
#pragma unroll
    for (int sub = 0; sub < 4; ++sub) {
      s16x8 k0 = *(const s16x8*)&ks[bufi][(sub * 16 + fr) * AP + fo];
      s16x8 k1 = *(const s16x8*)&ks[bufi][(sub * 16 + fr) * AP + 32 + fo];
      f32x4 acc = f32x4{0.f, 0.f, 0.f, 0.f};
      acc = __builtin_amdgcn_mfma_f32_16x16x32_bf16(k0, q0f, acc, 0, 0, 0);
      acc = __builtin_amdgcn_mfma_f32_16x16x32_bf16(k1, q1f, acc, 0, 0, 0);
      sv[sub] = acc;
    }
    const int qg = tq0 + wave * 16 + fr;
    if (diag) {
#pragma unroll
      for (int sub = 0; sub < 4; ++sub)
#pragma unroll
        for (int j = 0; j < 4; ++j)
          if (kt + sub * 16 + crow + j > qg) sv[sub][j] = -1e30f;
    }
    float g0 = fmaxf(fmaxf(sv[0][0], sv[0][1]), fmaxf(sv[0][2], sv[0][3]));
    float g1 = fmaxf(fmaxf(sv[1][0], sv[1][1]), fmaxf(sv[1][2], sv[1][3]));
    float g2 = fmaxf(fmaxf(sv[2][0], sv[2][1]), fmaxf(sv[2][2], sv[2][3]));
    float g3 = fmaxf(fmaxf(sv[3][0], sv[3][1]), fmaxf(sv[3][2], sv[3][3]));
    float t = fmaxf(fmaxf(g0, g1), fmaxf(g2, g3));
    t = fmaxf(t, __shfl_xor(t, 16));
    t = fmaxf(t, __shfl_xor(t, 32));
    const bool resc = t > m_ + 8.0f;  // T13 defer-max
    const float corr = resc ? exp2f(m_ - t) : 1.0f;
    if (resc) m_ = t;
    float rs = 0.f;
#pragma unroll
    for (int sub = 0; sub < 4; ++sub) {
      float p0 = exp2f(sv[sub][0] - m_);
      float p1 = exp2f(sv[sub][1] - m_);
      float p2 = exp2f(sv[sub][2] - m_);
      float p3 = exp2f(sv[sub][3] - m_);
      rs += (p0 + p1) + (p2 + p3);
      __hip_bfloat162 pk01 = __float22bfloat162_rn(float2{p0, p1});
      __hip_bfloat162 pk23 = __float22bfloat162_rn(float2{p2, p3});
      uint2 u;
      u.x = *reinterpret_cast<unsigned*>(&pk01);
      u.y = *reinterpret_cast<unsigned*>(&pk23);
      *(uint2*)&ps[wave][fr * AP + sub * 16 + crow] = u;  // ds_write_b64
    }
    rs += __shfl_xor(rs, 16);
    rs += __shfl_xor(rs, 32);
    l_ = l_ * corr + rs;
    if (__any(resc)) {
#pragma unroll
      for (int j = 0; j < 4; ++j) {
        const float cj = __shfl(corr, (lane & 0x30) | (crow + j));
#pragma unroll
        for (int ds = 0; ds < 4; ++ds) o[ds][j] *= cj;
      }
    }
    s16x8 pf0 = *(const s16x8*)&ps[wave][fr * AP + fo];
    s16x8 pf1 = *(const s16x8*)&ps[wave][fr * AP + 32 + fo];
#pragma unroll
    for (int ds = 0; ds < 4; ++ds) {
      s16x8 v0 = *(const s16x8*)&vt[bufi][(ds * 16 + fr) * AP + fo];
      s16x8 v1 = *(const s16x8*)&vt[bufi][(ds * 16 + fr) * AP + 32 + fo];
      o[ds] = __builtin_amdgcn_mfma_f32_16x16x32_bf16(pf0, v0, o[ds], 0, 0, 0);
      o[ds] = __builtin_amdgcn_mfma_f32_16x16x32_bf16(pf1, v1, o[ds], 0, 0, 0);
    }
  };

  loadKV(0);
  writeKV(0);
  __syncthreads();
  int cur = 0;
  for (int kt = 0; kt <= qb0; kt += 64) {
    const bool hasnext = (kt + 64 <= qb0);
    if (hasnext) loadKV(kt + 64);
    if (kt <= qa0)
      process(cur, qfa0, qfa1, oa, m_a, l_a, qa0, kt == qa0, kt);
    process(cur, qfb0, qfb1, ob, m_b, l_b, qb0, kt == qb0, kt);
    if (hasnext) writeKV(cur ^ 1);
    __syncthreads();
    cur ^= 1;
  }

#pragma unroll
  for (int j = 0; j < 4; ++j) {
    const float la_j = __shfl(l_a, (lane & 0x30) | (crow + j));
    const float lb_j = __shfl(l_b, (lane & 0x30) | (crow + j));
    const float inva = 1.0f / la_j;
    const float invb = 1.0f / lb_j;
    __hip_bfloat16* ya =
        y + (size_t)(b * T + qa0 + wave * 16 + crow + j) * N_EMBD + h * HEAD_DIM;
    __hip_bfloat16* yb =
        y + (size_t)(b * T + qb0 + wave * 16 + crow + j) * N_EMBD + h * HEAD_DIM;
#pragma unroll
    for (int ds = 0; ds < 4; ++ds) {
      ya[ds * 16 + fr] = __float2bfloat16(oa[ds][j] * inva);
      yb[ds * 16 + fr] = __float2bfloat16(ob[ds][j] * invb);
    }
  }
}

// ---------------- launch ----------------
extern "C" void kernel_launch(void* const* d_in, const int* in_sizes, int n_in,
                              void* d_out, int out_size, void* d_ws,
                              size_t ws_size, hipStream_t stream) {
  const int B = 4, T = 2048, C = N_EMBD;
  const int M = B * T;  // 8192

  const float* x      = (const float*)d_in[0];
  const float* ln1_g  = (const float*)d_in[1];
  const float* ln1_b  = (const float*)d_in[2];
  const float* attn_w = (const float*)d_in[3];
  const float* attn_b = (const float*)d_in[4];
  const float* proj_w = (const float*)d_in[5];
  const float* proj_b = (const float*)d_in[6];
  const float* ln2_g  = (const float*)d_in[7];
  const float* ln2_b  = (const float*)d_in[8];
  const float* fc_w   = (const float*)d_in[9];
  const float* fc_b   = (const float*)d_in[10];
  const float* fc2_w  = (const float*)d_in[11];
  const float* fc2_b  = (const float*)d_in[12];
  float* out = (float*)d_out;

  char* p = (char*)d_ws;
  size_t off = 0;
  auto take = [&](size_t bytes) -> void* {
    void* q = p + off;
    off += (bytes + 1023) & ~(size_t)1023;
    return q;
  };

  __hip_bfloat16* wqkv  = (__hip_bfloat16*)take((size_t)3 * C * C * 2);
  __hip_bfloat16* wproj = (__hip_bfloat16*)take((size_t)C * C * 2);
  __hip_bfloat16* wfc   = (__hip_bfloat16*)take((size_t)4 * C * C * 2);
  __hip_bfloat16* wfc2  = (__hip_bfloat16*)take((size_t)4 * C * C * 2);
  __hip_bfloat16* hbuf  = (__hip_bfloat16*)take((size_t)M * C * 2);
  __hip_bfloat16* big   = (__hip_bfloat16*)take((size_t)M * 4 * C * 2);
  __hip_bfloat16* ybuf  = (__hip_bfloat16*)take((size_t)M * C * 2);
  float*          x1    = (float*)take((size_t)M * C * 4);

  {
    const int n0 = 3 * C * C, n1 = C * C, n2 = 4 * C * C, n3 = 4 * C * C;
    const int ntot = n0 + n1 + n2 + n3;
    cvt4_kernel<<<(ntot + 255) / 256, 256, 0, stream>>>(
        attn_w, wqkv, proj_w, wproj, fc_w, wfc, fc2_w, wfc2, n0, n1, n2, n3);
  }

  ln_kernel<<<M, 256, 0, stream>>>(x, ln1_g, ln1_b, hbuf);
  gemm_bt<0><<<dim3(3 * C / TILE_N, M / TILE_M), 256, 0, stream>>>(
      hbuf, wqkv, attn_b, nullptr, big, nullptr, M, 3 * C, C);
  attn_mfma<<<dim3(T / 128, B * N_HEADS), 256, 0, stream>>>(big, ybuf, T);
  gemm_bt<2><<<dim3(C / TILE_N, M / TILE_M), 256, 0, stream>>>(
      ybuf, wproj, proj_b, x, nullptr, x1, M, C, C);
  ln_kernel<<<M, 256, 0, stream>>>(x1, ln2_g, ln2_b, hbuf);
  gemm_bt<1><<<dim3(4 * C / TILE_N, M / TILE_M), 256, 0, stream>>>(
      hbuf, wfc, fc_b, nullptr, big, nullptr, M, 4 * C, C);
  gemm_bt<2><<<dim3(C / TILE_N, M / TILE_M), 256, 0, stream>>>(
      big, wfc2, fc2_b, x1, nullptr, out, M, C, 4 * C);
}